// Round 4
// baseline (3809.716 us; speedup 1.0000x reference)
//
#include <hip/hip_runtime.h>
#include <hip/hip_bf16.h>

typedef unsigned short u16;
typedef unsigned int u32;
typedef __bf16 bf16x8 __attribute__((ext_vector_type(8)));
typedef float f32x4 __attribute__((ext_vector_type(4)));
typedef unsigned int u32x4 __attribute__((ext_vector_type(4)));

#define TXT 512
#define SEQ 2048
#define STOT 2560
#define DIM 3072
#define NH 24
#define HD 128
#define SOFTMAX_SCALE 0.08838834764831845f

__device__ __forceinline__ float b2f(u16 u) {
    union { u32 i; float f; } c; c.i = ((u32)u) << 16; return c.f;
}
__device__ __forceinline__ u16 f2b(float f) {
    union { float f; u32 i; } c; c.f = f;
    u32 x = c.i;
    return (u16)((x + 0x7FFFu + ((x >> 16) & 1u)) >> 16);
}
// pack two fp32 -> one u32 of two bf16 (RNE); low 16 = a, high 16 = b
__device__ __forceinline__ u32 pk2(float a, float b) {
    __hip_bfloat162 h = __float22bfloat162_rn(make_float2(a, b));
    return *reinterpret_cast<u32*>(&h);
}

// ---------------------------------------------------------------------------
// GEMM: C[M,N] = A[M,K] @ W[K,N] + bias[N]. W/bias fp32. fp32 accum, bf16
// MFMA. AF32: A is fp32 (else bf16 ws). OUTF32: C fp32 (else bf16 ws).
// 128x128 tile, BK=32, 4 waves (2x2), each 64x64 via 4x4 MFMA 16x16x32.
// ---------------------------------------------------------------------------
template<int AF32, int OUTF32>
__global__ __launch_bounds__(256, 2) void gemm_bias_kernel(
    const void* __restrict__ Av, const float* __restrict__ W,
    const float* __restrict__ bias, void* __restrict__ Cv, size_t coff,
    int M, int K, int N)
{
    __shared__ u16 As[128][40];   // [m][k], +8 pad keeps 16B align
    __shared__ u16 Bs[128][40];   // [n][k] transposed

    const int t    = threadIdx.x;
    const int lane = t & 63;
    const int wave = t >> 6;
    const int wr   = wave >> 1;
    const int wc   = wave & 1;
    const int m0   = blockIdx.x * 128;
    const int n0   = blockIdx.y * 128;
    const int fm   = lane & 15;
    const int fq   = lane >> 4;

    const int arow = t >> 1;          // 0..127
    const int akg  = (t & 1) * 16;    // 0 or 16
    const int bn   = t >> 1;          // 0..127
    const int bkg  = (t & 1) * 16;    // 0 or 16

    f32x4 acc[4][4];
    #pragma unroll
    for (int i = 0; i < 4; i++)
        #pragma unroll
        for (int j = 0; j < 4; j++)
            acc[i][j] = (f32x4){0.f, 0.f, 0.f, 0.f};

    for (int k0 = 0; k0 < K; k0 += 32) {
        // ---- A fragment (16 consecutive k elements) ----
        u32x4 a0, a1;
        if (AF32) {
            const f32x4* p = reinterpret_cast<const f32x4*>(
                (const float*)Av + (size_t)(m0 + arow) * K + k0 + akg);
            f32x4 x0 = p[0], x1 = p[1], x2 = p[2], x3 = p[3];
            a0 = (u32x4){pk2(x0[0], x0[1]), pk2(x0[2], x0[3]),
                         pk2(x1[0], x1[1]), pk2(x1[2], x1[3])};
            a1 = (u32x4){pk2(x2[0], x2[1]), pk2(x2[2], x2[3]),
                         pk2(x3[0], x3[1]), pk2(x3[2], x3[3])};
        } else {
            const u32x4* p = reinterpret_cast<const u32x4*>(
                (const u16*)Av + (size_t)(m0 + arow) * K + k0 + akg);
            a0 = p[0]; a1 = p[1];
        }
        // ---- W fragment (16 k-rows, one n-column each) ----
        float wv[16];
        #pragma unroll
        for (int j = 0; j < 16; j++)
            wv[j] = W[(size_t)(k0 + bkg + j) * N + n0 + bn];
        u32x4 b0, b1;
        #pragma unroll
        for (int j = 0; j < 4; j++) {
            b0[j] = pk2(wv[2 * j],     wv[2 * j + 1]);
            b1[j] = pk2(wv[8 + 2 * j], wv[8 + 2 * j + 1]);
        }
        __syncthreads();   // previous iteration's LDS reads complete
        *reinterpret_cast<u32x4*>(&As[arow][akg])     = a0;
        *reinterpret_cast<u32x4*>(&As[arow][akg + 8]) = a1;
        *reinterpret_cast<u32x4*>(&Bs[bn][bkg])       = b0;
        *reinterpret_cast<u32x4*>(&Bs[bn][bkg + 8])   = b1;
        __syncthreads();

        bf16x8 af[4], bfr[4];
        #pragma unroll
        for (int i = 0; i < 4; i++)
            af[i] = *reinterpret_cast<const bf16x8*>(&As[wr * 64 + i * 16 + fm][fq * 8]);
        #pragma unroll
        for (int j = 0; j < 4; j++)
            bfr[j] = *reinterpret_cast<const bf16x8*>(&Bs[wc * 64 + j * 16 + fm][fq * 8]);
        #pragma unroll
        for (int i = 0; i < 4; i++)
            #pragma unroll
            for (int j = 0; j < 4; j++)
                acc[i][j] = __builtin_amdgcn_mfma_f32_16x16x32_bf16(af[i], bfr[j], acc[i][j], 0, 0, 0);
    }

    // epilogue: C/D layout col = lane&15, row = (lane>>4)*4 + r
    #pragma unroll
    for (int i = 0; i < 4; i++) {
        #pragma unroll
        for (int j = 0; j < 4; j++) {
            int col = n0 + wc * 64 + j * 16 + fm;
            float bb = bias[col];
            #pragma unroll
            for (int r = 0; r < 4; r++) {
                int row = m0 + wr * 64 + i * 16 + fq * 4 + r;
                size_t idx = coff + (size_t)row * N + col;
                float val = acc[i][j][r] + bb;
                if (OUTF32) ((float*)Cv)[idx] = val;
                else        ((u16*)Cv)[idx]   = f2b(val);
            }
        }
    }
}

// ---------------------------------------------------------------------------
// Fused per-head RMSNorm + interleaved RoPE, in place on bf16 Q/K buffers.
// One wave per (head, token, which); thread t owns dims 2t, 2t+1.
// ---------------------------------------------------------------------------
__global__ __launch_bounds__(64) void rmsrope_kernel(
    u16* __restrict__ Qf, u16* __restrict__ Kf,
    const float* __restrict__ nq, const float* __restrict__ nk,
    const float* __restrict__ naq, const float* __restrict__ nak,
    const float* __restrict__ cosb, const float* __restrict__ sinb)
{
    const int h     = blockIdx.x;
    const int tok   = blockIdx.y;
    const int which = blockIdx.z;   // 0 = Q, 1 = K
    u16* buf = which ? Kf : Qf;
    const float* nw = (tok < TXT) ? (which ? nak : naq) : (which ? nk : nq);
    const int t = threadIdx.x;
    const size_t base = (size_t)tok * DIM + h * HD + 2 * t;

    u32 pr = *reinterpret_cast<const u32*>(&buf[base]);
    float x0 = b2f((u16)(pr & 0xFFFF));
    float x1 = b2f((u16)(pr >> 16));

    float ss = x0 * x0 + x1 * x1;
    #pragma unroll
    for (int off = 32; off; off >>= 1) ss += __shfl_xor(ss, off);
    float r = rsqrtf(ss * (1.0f / 128.0f) + 1e-6f);

    float y0 = x0 * r * nw[2 * t];
    float y1 = x1 * r * nw[2 * t + 1];
    float c0 = cosb[tok * HD + 2 * t];
    float c1 = cosb[tok * HD + 2 * t + 1];
    float s0 = sinb[tok * HD + 2 * t];
    float s1 = sinb[tok * HD + 2 * t + 1];
    // out[2i] = x[2i]*cos - x[2i+1]*sin ; out[2i+1] = x[2i+1]*cos + x[2i]*sin
    float o0 = y0 * c0 - y1 * s0;
    float o1 = y1 * c1 + y0 * s1;
    *reinterpret_cast<u32*>(&buf[base]) = pk2(o0, o1);
}

// ---------------------------------------------------------------------------
// Scalar flash attention, online softmax. One block = (head, 32-query tile).
// Ref queries [512,1024) see only ref keys; others see all 2560 keys.
// AO may alias Qf: block (q0,h) reads only its own Q tile (staged to LDS
// before any write) and writes exactly that region at the end.
// ---------------------------------------------------------------------------
__global__ __launch_bounds__(256, 2) void attn_kernel(
    const u16* __restrict__ Qf, const u16* __restrict__ Kf,
    const u16* __restrict__ Vf, u16* __restrict__ AO)
{
    __shared__ float Qs[32 * 132];
    __shared__ float Ks[32 * 132];
    __shared__ float Vs[32 * 132];
    __shared__ float Ss[32 * 33];

    const int qb = blockIdx.x;
    const int h  = blockIdx.y;
    const int q0 = qb * 32;
    const bool is_ref = (q0 >= TXT) && (q0 < TXT + 512);
    const int ks = is_ref ? TXT : 0;
    const int ke = is_ref ? (TXT + 512) : STOT;

    const int t    = threadIdx.x;
    const int srow = t >> 3;
    const int scol = (t & 7) * 16;
    const int qi   = t >> 3;
    const int kk   = t & 7;
    const int dg   = t & 7;

    {
        const u16* src = &Qf[(size_t)(q0 + srow) * DIM + h * HD + scol];
        #pragma unroll
        for (int i = 0; i < 16; i++)
            Qs[srow * 132 + scol + i] = b2f(src[i]) * SOFTMAX_SCALE;
    }

    float m = -1e30f, l = 0.0f;
    f32x4 o[4];
    #pragma unroll
    for (int i = 0; i < 4; i++) o[i] = (f32x4){0.f, 0.f, 0.f, 0.f};

    for (int k0 = ks; k0 < ke; k0 += 32) {
        __syncthreads();
        {
            const u16* ksrc = &Kf[(size_t)(k0 + srow) * DIM + h * HD + scol];
            const u16* vsrc = &Vf[(size_t)(k0 + srow) * DIM + h * HD + scol];
            #pragma unroll
            for (int i = 0; i < 16; i++) {
                Ks[srow * 132 + scol + i] = b2f(ksrc[i]);
                Vs[srow * 132 + scol + i] = b2f(vsrc[i]);
            }
        }
        __syncthreads();

        f32x4 a0v = {0.f,0.f,0.f,0.f}, a1v = {0.f,0.f,0.f,0.f};
        f32x4 a2v = {0.f,0.f,0.f,0.f}, a3v = {0.f,0.f,0.f,0.f};
        {
            const f32x4* qp  = reinterpret_cast<const f32x4*>(&Qs[qi * 132]);
            const f32x4* kp0 = reinterpret_cast<const f32x4*>(&Ks[(kk +  0) * 132]);
            const f32x4* kp1 = reinterpret_cast<const f32x4*>(&Ks[(kk +  8) * 132]);
            const f32x4* kp2 = reinterpret_cast<const f32x4*>(&Ks[(kk + 16) * 132]);
            const f32x4* kp3 = reinterpret_cast<const f32x4*>(&Ks[(kk + 24) * 132]);
            #pragma unroll 4
            for (int d = 0; d < 32; d++) {
                f32x4 qv = qp[d];
                a0v += qv * kp0[d];
                a1v += qv * kp1[d];
                a2v += qv * kp2[d];
                a3v += qv * kp3[d];
            }
        }
        float sc[4];
        sc[0] = a0v[0] + a0v[1] + a0v[2] + a0v[3];
        sc[1] = a1v[0] + a1v[1] + a1v[2] + a1v[3];
        sc[2] = a2v[0] + a2v[1] + a2v[2] + a2v[3];
        sc[3] = a3v[0] + a3v[1] + a3v[2] + a3v[3];

        float tmax = fmaxf(fmaxf(sc[0], sc[1]), fmaxf(sc[2], sc[3]));
        tmax = fmaxf(tmax, __shfl_xor(tmax, 1));
        tmax = fmaxf(tmax, __shfl_xor(tmax, 2));
        tmax = fmaxf(tmax, __shfl_xor(tmax, 4));
        float mnew  = fmaxf(m, tmax);
        float alpha = __expf(m - mnew);
        float p[4];
        float psum = 0.f;
        #pragma unroll
        for (int j = 0; j < 4; j++) { p[j] = __expf(sc[j] - mnew); psum += p[j]; }
        psum += __shfl_xor(psum, 1);
        psum += __shfl_xor(psum, 2);
        psum += __shfl_xor(psum, 4);
        l = l * alpha + psum;
        m = mnew;
        #pragma unroll
        for (int j = 0; j < 4; j++) Ss[qi * 33 + kk + 8 * j] = p[j];
        #pragma unroll
        for (int i = 0; i < 4; i++) o[i] *= alpha;
        __syncthreads();

        #pragma unroll 8
        for (int k = 0; k < 32; k++) {
            float pv = Ss[qi * 33 + k];
            const f32x4* vp = reinterpret_cast<const f32x4*>(&Vs[k * 132 + dg * 16]);
            #pragma unroll
            for (int i = 0; i < 4; i++) o[i] += pv * vp[i];
        }
    }

    float inv = 1.0f / l;
    u16* dst = &AO[(size_t)(q0 + qi) * DIM + h * HD + dg * 16];
    #pragma unroll
    for (int i = 0; i < 4; i++)
        #pragma unroll
        for (int c = 0; c < 4; c++)
            dst[i * 4 + c] = f2b(o[i][c] * inv);
}

// ---------------------------------------------------------------------------
// Buffer plan (ws-size-safe; only 15.7 MB of d_ws used):
//   Qf  = d_ws                          [STOT*DIM bf16]  (doubles as AO)
//   Kf  = d_out bytes [0, 15728640)     [STOT*DIM bf16]  (dead before d_out
//   Vf  = d_out bytes [15728640, ...)   [STOT*DIM bf16]   is overwritten)
// K/V live in d_out because its 31.4 MB is exactly 2 buffers; the output
// GEMMs run last and clobber them after their final read (attn).
// ---------------------------------------------------------------------------
extern "C" void kernel_launch(void* const* d_in, const int* in_sizes, int n_in,
                              void* d_out, int out_size, void* d_ws, size_t ws_size,
                              hipStream_t stream)
{
    const void*  hs  = d_in[0];
    const void*  enc = d_in[1];
    const float* rc  = (const float*)d_in[2];
    const float* rs  = (const float*)d_in[3];
    const float* wq  = (const float*)d_in[4];  const float* bq  = (const float*)d_in[5];
    const float* wk  = (const float*)d_in[6];  const float* bk  = (const float*)d_in[7];
    const float* wv  = (const float*)d_in[8];  const float* bv  = (const float*)d_in[9];
    const float* waq = (const float*)d_in[10]; const float* baq = (const float*)d_in[11];
    const float* wak = (const float*)d_in[12]; const float* bak = (const float*)d_in[13];
    const float* wav = (const float*)d_in[14]; const float* bav = (const float*)d_in[15];
    const float* nq  = (const float*)d_in[16]; const float* nk  = (const float*)d_in[17];
    const float* naq = (const float*)d_in[18]; const float* nak = (const float*)d_in[19];
    const float* wo  = (const float*)d_in[20]; const float* bo  = (const float*)d_in[21];
    const float* wao = (const float*)d_in[22]; const float* bao = (const float*)d_in[23];

    u16* Qf = (u16*)d_ws;
    u16* Kf = (u16*)d_out;
    u16* Vf = (u16*)d_out + (size_t)STOT * DIM;
    u16* AO = Qf;   // in-place: each attn block reads only the tile it writes

    dim3 blk(256);
    // projections: fp32 A -> bf16, concat layout [txt | ref+img]
    gemm_bias_kernel<1,0><<<dim3(SEQ / 128, DIM / 128), blk, 0, stream>>>(hs, wq, bq, Qf, (size_t)TXT * DIM, SEQ, DIM, DIM);
    gemm_bias_kernel<1,0><<<dim3(SEQ / 128, DIM / 128), blk, 0, stream>>>(hs, wk, bk, Kf, (size_t)TXT * DIM, SEQ, DIM, DIM);
    gemm_bias_kernel<1,0><<<dim3(SEQ / 128, DIM / 128), blk, 0, stream>>>(hs, wv, bv, Vf, (size_t)TXT * DIM, SEQ, DIM, DIM);
    gemm_bias_kernel<1,0><<<dim3(TXT / 128, DIM / 128), blk, 0, stream>>>(enc, waq, baq, Qf, 0, TXT, DIM, DIM);
    gemm_bias_kernel<1,0><<<dim3(TXT / 128, DIM / 128), blk, 0, stream>>>(enc, wak, bak, Kf, 0, TXT, DIM, DIM);
    gemm_bias_kernel<1,0><<<dim3(TXT / 128, DIM / 128), blk, 0, stream>>>(enc, wav, bav, Vf, 0, TXT, DIM, DIM);
    // fused RMSNorm + RoPE on Q and K, in place
    rmsrope_kernel<<<dim3(NH, STOT, 2), dim3(64), 0, stream>>>(Qf, Kf, nq, nk, naq, nak, rc, rs);
    // structured attention (AO aliases Qf)
    attn_kernel<<<dim3(STOT / 32, NH), blk, 0, stream>>>(Qf, Kf, Vf, AO);
    // output projections: bf16 AO -> fp32 d_out (clobbers Kf/Vf, now dead).
    gemm_bias_kernel<0,1><<<dim3(SEQ / 128, DIM / 128), blk, 0, stream>>>(AO + (size_t)TXT * DIM, wo, bo, d_out, 0, SEQ, DIM, DIM);
    gemm_bias_kernel<0,1><<<dim3(TXT / 128, DIM / 128), blk, 0, stream>>>(AO, wao, bao, d_out, (size_t)SEQ * DIM, TXT, DIM, DIM);
}

// Round 5
// 1775.389 us; speedup vs baseline: 2.1458x; 2.1458x over previous
//
#include <hip/hip_runtime.h>
#include <hip/hip_bf16.h>

typedef unsigned short u16;
typedef unsigned int u32;
typedef __bf16 bf16x8 __attribute__((ext_vector_type(8)));
typedef float f32x4 __attribute__((ext_vector_type(4)));
typedef unsigned int u32x4 __attribute__((ext_vector_type(4)));
typedef unsigned int u32x2 __attribute__((ext_vector_type(2)));

#define TXT 512
#define SEQ 2048
#define STOT 2560
#define DIM 3072
#define NH 24
#define HD 128
#define SOFTMAX_SCALE 0.08838834764831845f

__device__ __forceinline__ float b2f(u16 u) {
    union { u32 i; float f; } c; c.i = ((u32)u) << 16; return c.f;
}
__device__ __forceinline__ u16 f2b(float f) {
    union { float f; u32 i; } c; c.f = f;
    u32 x = c.i;
    return (u16)((x + 0x7FFFu + ((x >> 16) & 1u)) >> 16);
}
// pack two fp32 -> one u32 of two bf16 (RNE); low 16 = a, high 16 = b
__device__ __forceinline__ u32 pk2(float a, float b) {
    __hip_bfloat162 h = __float22bfloat162_rn(make_float2(a, b));
    return *reinterpret_cast<u32*>(&h);
}
__device__ __forceinline__ f32x4 max4(f32x4 a, f32x4 b) {
    return (f32x4){fmaxf(a[0], b[0]), fmaxf(a[1], b[1]),
                   fmaxf(a[2], b[2]), fmaxf(a[3], b[3])};
}
__device__ __forceinline__ f32x4 shfl_xor4(f32x4 v, int mask) {
    return (f32x4){__shfl_xor(v[0], mask), __shfl_xor(v[1], mask),
                   __shfl_xor(v[2], mask), __shfl_xor(v[3], mask)};
}

// ---------------------------------------------------------------------------
// GEMM: C = A[M,K] @ W[K,N] + bias[N]. W/bias fp32. fp32 accum, bf16 MFMA.
// AF32: A fp32 (else bf16). OUTMODE: 0 = bf16 row-major (coff = elem offset),
// 1 = fp32 row-major (coff = elem offset), 2 = bf16 TRANSPOSED [N][STOT]
// (coff = token offset) -- used to produce global V^T for attention.
// ---------------------------------------------------------------------------
template<int AF32, int OUTMODE>
__global__ __launch_bounds__(256, 2) void gemm_bias_kernel(
    const void* __restrict__ Av, const float* __restrict__ W,
    const float* __restrict__ bias, void* __restrict__ Cv, size_t coff,
    int M, int K, int N)
{
    __shared__ u16 As[128][40];   // [m][k], +8 pad keeps 16B align
    __shared__ u16 Bs[128][40];   // [n][k] transposed

    const int t    = threadIdx.x;
    const int lane = t & 63;
    const int wave = t >> 6;
    const int wr   = wave >> 1;
    const int wc   = wave & 1;
    const int m0   = blockIdx.x * 128;
    const int n0   = blockIdx.y * 128;
    const int fm   = lane & 15;
    const int fq   = lane >> 4;

    const int arow = t >> 1;          // 0..127
    const int akg  = (t & 1) * 16;    // 0 or 16
    const int bn   = t >> 1;          // 0..127
    const int bkg  = (t & 1) * 16;    // 0 or 16

    f32x4 acc[4][4];
    #pragma unroll
    for (int i = 0; i < 4; i++)
        #pragma unroll
        for (int j = 0; j < 4; j++)
            acc[i][j] = (f32x4){0.f, 0.f, 0.f, 0.f};

    for (int k0 = 0; k0 < K; k0 += 32) {
        u32x4 a0, a1;
        if (AF32) {
            const f32x4* p = reinterpret_cast<const f32x4*>(
                (const float*)Av + (size_t)(m0 + arow) * K + k0 + akg);
            f32x4 x0 = p[0], x1 = p[1], x2 = p[2], x3 = p[3];
            a0 = (u32x4){pk2(x0[0], x0[1]), pk2(x0[2], x0[3]),
                         pk2(x1[0], x1[1]), pk2(x1[2], x1[3])};
            a1 = (u32x4){pk2(x2[0], x2[1]), pk2(x2[2], x2[3]),
                         pk2(x3[0], x3[1]), pk2(x3[2], x3[3])};
        } else {
            const u32x4* p = reinterpret_cast<const u32x4*>(
                (const u16*)Av + (size_t)(m0 + arow) * K + k0 + akg);
            a0 = p[0]; a1 = p[1];
        }
        float wv[16];
        #pragma unroll
        for (int j = 0; j < 16; j++)
            wv[j] = W[(size_t)(k0 + bkg + j) * N + n0 + bn];
        u32x4 b0, b1;
        #pragma unroll
        for (int j = 0; j < 4; j++) {
            b0[j] = pk2(wv[2 * j],     wv[2 * j + 1]);
            b1[j] = pk2(wv[8 + 2 * j], wv[8 + 2 * j + 1]);
        }
        __syncthreads();
        *reinterpret_cast<u32x4*>(&As[arow][akg])     = a0;
        *reinterpret_cast<u32x4*>(&As[arow][akg + 8]) = a1;
        *reinterpret_cast<u32x4*>(&Bs[bn][bkg])       = b0;
        *reinterpret_cast<u32x4*>(&Bs[bn][bkg + 8])   = b1;
        __syncthreads();

        bf16x8 af[4], bfr[4];
        #pragma unroll
        for (int i = 0; i < 4; i++)
            af[i] = *reinterpret_cast<const bf16x8*>(&As[wr * 64 + i * 16 + fm][fq * 8]);
        #pragma unroll
        for (int j = 0; j < 4; j++)
            bfr[j] = *reinterpret_cast<const bf16x8*>(&Bs[wc * 64 + j * 16 + fm][fq * 8]);
        #pragma unroll
        for (int i = 0; i < 4; i++)
            #pragma unroll
            for (int j = 0; j < 4; j++)
                acc[i][j] = __builtin_amdgcn_mfma_f32_16x16x32_bf16(af[i], bfr[j], acc[i][j], 0, 0, 0);
    }

    // epilogue: C/D layout col = lane&15, row = (lane>>4)*4 + r
    #pragma unroll
    for (int i = 0; i < 4; i++) {
        #pragma unroll
        for (int j = 0; j < 4; j++) {
            int col = n0 + wc * 64 + j * 16 + fm;
            float bb = bias[col];
            if (OUTMODE == 2) {
                // transposed bf16: VT[col][token], 4 consecutive tokens packed
                int tok = (int)coff + m0 + wr * 64 + i * 16 + fq * 4;
                u32x2 pr = {pk2(acc[i][j][0] + bb, acc[i][j][1] + bb),
                            pk2(acc[i][j][2] + bb, acc[i][j][3] + bb)};
                *reinterpret_cast<u32x2*>(&((u16*)Cv)[(size_t)col * STOT + tok]) = pr;
            } else {
                #pragma unroll
                for (int r = 0; r < 4; r++) {
                    int row = m0 + wr * 64 + i * 16 + fq * 4 + r;
                    size_t idx = coff + (size_t)row * N + col;
                    float val = acc[i][j][r] + bb;
                    if (OUTMODE == 1) ((float*)Cv)[idx] = val;
                    else              ((u16*)Cv)[idx]   = f2b(val);
                }
            }
        }
    }
}

// ---------------------------------------------------------------------------
// Fused per-head RMSNorm + interleaved RoPE, in place on bf16 Q/K buffers.
// ---------------------------------------------------------------------------
__global__ __launch_bounds__(64) void rmsrope_kernel(
    u16* __restrict__ Qf, u16* __restrict__ Kf,
    const float* __restrict__ nq, const float* __restrict__ nk,
    const float* __restrict__ naq, const float* __restrict__ nak,
    const float* __restrict__ cosb, const float* __restrict__ sinb)
{
    const int h     = blockIdx.x;
    const int tok   = blockIdx.y;
    const int which = blockIdx.z;   // 0 = Q, 1 = K
    u16* buf = which ? Kf : Qf;
    const float* nw = (tok < TXT) ? (which ? nak : naq) : (which ? nk : nq);
    const int t = threadIdx.x;
    const size_t base = (size_t)tok * DIM + h * HD + 2 * t;

    u32 pr = *reinterpret_cast<const u32*>(&buf[base]);
    float x0 = b2f((u16)(pr & 0xFFFF));
    float x1 = b2f((u16)(pr >> 16));

    float ss = x0 * x0 + x1 * x1;
    #pragma unroll
    for (int off = 32; off; off >>= 1) ss += __shfl_xor(ss, off);
    float r = rsqrtf(ss * (1.0f / 128.0f) + 1e-6f);

    float y0 = x0 * r * nw[2 * t];
    float y1 = x1 * r * nw[2 * t + 1];
    float c0 = cosb[tok * HD + 2 * t];
    float c1 = cosb[tok * HD + 2 * t + 1];
    float s0 = sinb[tok * HD + 2 * t];
    float s1 = sinb[tok * HD + 2 * t + 1];
    float o0 = y0 * c0 - y1 * s0;
    float o1 = y1 * c1 + y0 * s1;
    *reinterpret_cast<u32*>(&buf[base]) = pk2(o0, o1);
}

// ---------------------------------------------------------------------------
// MFMA flash attention. Block = 256 thr (4 waves) = 64 queries x 1 head;
// wave w owns queries q0+w*16..+16. K-tile = 64 keys.
//   QK^T: A = Q (registers, from global), B = K (LDS row-major [tok][d]).
//   Softmax: C-layout rows q=quad*4+r -> m/l as f32x4, 16-lane xor reduce.
//   P: C-layout -> per-wave LDS [q][key] -> re-read as A-fragments.
//   PV: B = V^T (LDS [d][key], staged from global VT produced by V-GEMM).
// Ref queries [512,1024) attend only to ref keys; others to all 2560.
// AO aliases Qf: Q is consumed into registers before any O write.
// ---------------------------------------------------------------------------
__global__ __launch_bounds__(256, 2) void attn_kernel(
    const u16* __restrict__ Qf, const u16* __restrict__ Kf,
    const u16* __restrict__ VTg, u16* __restrict__ AO)
{
    __shared__ u16 Ks[64][136];     // [key][d]   (+8 pad)
    __shared__ u16 VTs[128][72];    // [d][key]   (+8 pad)
    __shared__ u16 Ps[4][16][72];   // per-wave P [q][key] (+8 pad)

    const int t    = threadIdx.x;
    const int w    = t >> 6;
    const int lane = t & 63;
    const int col  = lane & 15;
    const int quad = lane >> 4;
    const int h    = blockIdx.y;
    const int q0   = blockIdx.x * 64;
    const bool is_ref = (q0 >= TXT) && (q0 < TXT + 512);
    const int ks = is_ref ? TXT : 0;
    const int ke = is_ref ? (TXT + 512) : STOT;

    // Q A-fragments: row q = q0 + w*16 + col, d-chunks of 32
    const size_t qbase = (size_t)(q0 + w * 16 + col) * DIM + h * HD;
    bf16x8 Qfrag[4];
    #pragma unroll
    for (int c = 0; c < 4; c++)
        Qfrag[c] = *reinterpret_cast<const bf16x8*>(&Qf[qbase + c * 32 + quad * 8]);

    f32x4 O[8];
    #pragma unroll
    for (int dt = 0; dt < 8; dt++) O[dt] = (f32x4){0.f, 0.f, 0.f, 0.f};
    f32x4 m = (f32x4){-1e30f, -1e30f, -1e30f, -1e30f};
    f32x4 l = (f32x4){0.f, 0.f, 0.f, 0.f};

    const int krow = t >> 2, kseg = t & 3;   // K stage: 64 rows x 4 segs of 32
    const int vrow = t >> 1, vseg = t & 1;   // VT stage: 128 rows x 2 segs of 32

    for (int k0 = ks; k0 < ke; k0 += 64) {
        __syncthreads();   // prior tile's LDS reads complete
        {
            const u32x4* src = reinterpret_cast<const u32x4*>(
                &Kf[(size_t)(k0 + krow) * DIM + h * HD + kseg * 32]);
            u32x4 v0 = src[0], v1 = src[1], v2 = src[2], v3 = src[3];
            u32x4* dst = reinterpret_cast<u32x4*>(&Ks[krow][kseg * 32]);
            dst[0] = v0; dst[1] = v1; dst[2] = v2; dst[3] = v3;
        }
        {
            const u32x4* src = reinterpret_cast<const u32x4*>(
                &VTg[(size_t)(h * HD + vrow) * STOT + k0 + vseg * 32]);
            u32x4 v0 = src[0], v1 = src[1], v2 = src[2], v3 = src[3];
            u32x4* dst = reinterpret_cast<u32x4*>(&VTs[vrow][vseg * 32]);
            dst[0] = v0; dst[1] = v1; dst[2] = v2; dst[3] = v3;
        }
        __syncthreads();

        // ---- S = scale * Q K^T : 4 key-subtiles of 16 ----
        f32x4 s[4];
        #pragma unroll
        for (int kt = 0; kt < 4; kt++) {
            f32x4 a = (f32x4){0.f, 0.f, 0.f, 0.f};
            #pragma unroll
            for (int c = 0; c < 4; c++) {
                bf16x8 kf = *reinterpret_cast<const bf16x8*>(
                    &Ks[kt * 16 + col][c * 32 + quad * 8]);
                a = __builtin_amdgcn_mfma_f32_16x16x32_bf16(Qfrag[c], kf, a, 0, 0, 0);
            }
            s[kt] = a * SOFTMAX_SCALE;
        }

        // ---- online softmax (rows = quad*4+r, reduce across 16 cols) ----
        f32x4 tmax = max4(max4(s[0], s[1]), max4(s[2], s[3]));
        tmax = max4(tmax, shfl_xor4(tmax, 1));
        tmax = max4(tmax, shfl_xor4(tmax, 2));
        tmax = max4(tmax, shfl_xor4(tmax, 4));
        tmax = max4(tmax, shfl_xor4(tmax, 8));
        f32x4 mnew = max4(m, tmax);
        f32x4 alpha, rowsum = (f32x4){0.f, 0.f, 0.f, 0.f};
        #pragma unroll
        for (int r = 0; r < 4; r++) alpha[r] = __expf(m[r] - mnew[r]);
        f32x4 p[4];
        #pragma unroll
        for (int kt = 0; kt < 4; kt++)
            #pragma unroll
            for (int r = 0; r < 4; r++) {
                p[kt][r] = __expf(s[kt][r] - mnew[r]);
                rowsum[r] += p[kt][r];
            }
        rowsum += shfl_xor4(rowsum, 1);
        rowsum += shfl_xor4(rowsum, 2);
        rowsum += shfl_xor4(rowsum, 4);
        rowsum += shfl_xor4(rowsum, 8);
        #pragma unroll
        for (int r = 0; r < 4; r++) l[r] = l[r] * alpha[r] + rowsum[r];
        m = mnew;
        #pragma unroll
        for (int dt = 0; dt < 8; dt++)
            #pragma unroll
            for (int r = 0; r < 4; r++) O[dt][r] *= alpha[r];

        // ---- P round trip (C-layout -> A-layout), per-wave region ----
        #pragma unroll
        for (int kt = 0; kt < 4; kt++)
            #pragma unroll
            for (int r = 0; r < 4; r++)
                Ps[w][quad * 4 + r][kt * 16 + col] = f2b(p[kt][r]);
        // same-wave LDS RAW: compiler inserts lgkmcnt wait; no barrier needed

        // ---- O += P V : 8 d-subtiles x 2 key-chunks ----
        #pragma unroll
        for (int c = 0; c < 2; c++) {
            bf16x8 pf = *reinterpret_cast<const bf16x8*>(
                &Ps[w][col][c * 32 + quad * 8]);
            #pragma unroll
            for (int dt = 0; dt < 8; dt++) {
                bf16x8 vf = *reinterpret_cast<const bf16x8*>(
                    &VTs[dt * 16 + col][c * 32 + quad * 8]);
                O[dt] = __builtin_amdgcn_mfma_f32_16x16x32_bf16(pf, vf, O[dt], 0, 0, 0);
            }
        }
    }

    // ---- epilogue: O / l -> AO (C-layout rows, coalesced 32B stores) ----
    f32x4 inv;
    #pragma unroll
    for (int r = 0; r < 4; r++) inv[r] = 1.0f / l[r];
    #pragma unroll
    for (int dt = 0; dt < 8; dt++)
        #pragma unroll
        for (int r = 0; r < 4; r++)
            AO[(size_t)(q0 + w * 16 + quad * 4 + r) * DIM + h * HD + dt * 16 + col] =
                f2b(O[dt][r] * inv[r]);
}

// ---------------------------------------------------------------------------
// Buffer plan (<= 15.7 MB of d_ws):
//   Qf  = d_ws                    [STOT*DIM bf16]   (doubles as AO)
//   Kf  = d_out lower half        [STOT*DIM bf16]   (dead before out-GEMMs)
//   VTg = d_out upper half        [DIM][STOT] bf16  V^T, written by V-GEMM
// ---------------------------------------------------------------------------
extern "C" void kernel_launch(void* const* d_in, const int* in_sizes, int n_in,
                              void* d_out, int out_size, void* d_ws, size_t ws_size,
                              hipStream_t stream)
{
    const void*  hs  = d_in[0];
    const void*  enc = d_in[1];
    const float* rc  = (const float*)d_in[2];
    const float* rs  = (const float*)d_in[3];
    const float* wq  = (const float*)d_in[4];  const float* bq  = (const float*)d_in[5];
    const float* wk  = (const float*)d_in[6];  const float* bk  = (const float*)d_in[7];
    const float* wv  = (const float*)d_in[8];  const float* bv  = (const float*)d_in[9];
    const float* waq = (const float*)d_in[10]; const float* baq = (const float*)d_in[11];
    const float* wak = (const float*)d_in[12]; const float* bak = (const float*)d_in[13];
    const float* wav = (const float*)d_in[14]; const float* bav = (const float*)d_in[15];
    const float* nq  = (const float*)d_in[16]; const float* nk  = (const float*)d_in[17];
    const float* naq = (const float*)d_in[18]; const float* nak = (const float*)d_in[19];
    const float* wo  = (const float*)d_in[20]; const float* bo  = (const float*)d_in[21];
    const float* wao = (const float*)d_in[22]; const float* bao = (const float*)d_in[23];

    u16* Qf  = (u16*)d_ws;
    u16* Kf  = (u16*)d_out;
    u16* VTg = (u16*)d_out + (size_t)STOT * DIM;
    u16* AO  = Qf;   // in-place: each attn block reads only the tile it writes

    dim3 blk(256);
    // projections: fp32 A -> bf16, concat layout [txt | ref+img]
    gemm_bias_kernel<1,0><<<dim3(SEQ / 128, DIM / 128), blk, 0, stream>>>(hs, wq, bq, Qf, (size_t)TXT * DIM, SEQ, DIM, DIM);
    gemm_bias_kernel<1,0><<<dim3(SEQ / 128, DIM / 128), blk, 0, stream>>>(hs, wk, bk, Kf, (size_t)TXT * DIM, SEQ, DIM, DIM);
    gemm_bias_kernel<1,2><<<dim3(SEQ / 128, DIM / 128), blk, 0, stream>>>(hs, wv, bv, VTg, (size_t)TXT, SEQ, DIM, DIM);
    gemm_bias_kernel<1,0><<<dim3(TXT / 128, DIM / 128), blk, 0, stream>>>(enc, waq, baq, Qf, 0, TXT, DIM, DIM);
    gemm_bias_kernel<1,0><<<dim3(TXT / 128, DIM / 128), blk, 0, stream>>>(enc, wak, bak, Kf, 0, TXT, DIM, DIM);
    gemm_bias_kernel<1,2><<<dim3(TXT / 128, DIM / 128), blk, 0, stream>>>(enc, wav, bav, VTg, 0, TXT, DIM, DIM);
    // fused RMSNorm + RoPE on Q and K, in place (V needs neither)
    rmsrope_kernel<<<dim3(NH, STOT, 2), dim3(64), 0, stream>>>(Qf, Kf, nq, nk, naq, nak, rc, rs);
    // MFMA flash attention (AO aliases Qf)
    attn_kernel<<<dim3(STOT / 64, NH), blk, 0, stream>>>(Qf, Kf, VTg, AO);
    // output projections: bf16 AO -> fp32 d_out (clobbers Kf/VTg, now dead)
    gemm_bias_kernel<0,1><<<dim3(SEQ / 128, DIM / 128), blk, 0, stream>>>(AO + (size_t)TXT * DIM, wo, bo, d_out, 0, SEQ, DIM, DIM);
    gemm_bias_kernel<0,1><<<dim3(TXT / 128, DIM / 128), blk, 0, stream>>>(AO, wao, bao, d_out, (size_t)SEQ * DIM, TXT, DIM, DIM);
}

// Round 6
// 1368.202 us; speedup vs baseline: 2.7845x; 1.2976x over previous
//
#include <hip/hip_runtime.h>
#include <hip/hip_bf16.h>

typedef unsigned short u16;
typedef unsigned int u32;
typedef __bf16 bf16x8 __attribute__((ext_vector_type(8)));
typedef float f32x4 __attribute__((ext_vector_type(4)));
typedef unsigned int u32x4 __attribute__((ext_vector_type(4)));
typedef unsigned int u32x2 __attribute__((ext_vector_type(2)));

#define TXT 512
#define SEQ 2048
#define STOT 2560
#define DIM 3072
#define NH 24
#define HD 128
#define SOFTMAX_SCALE 0.08838834764831845f

__device__ __forceinline__ float b2f(u16 u) {
    union { u32 i; float f; } c; c.i = ((u32)u) << 16; return c.f;
}
__device__ __forceinline__ u16 f2b(float f) {
    union { float f; u32 i; } c; c.f = f;
    u32 x = c.i;
    return (u16)((x + 0x7FFFu + ((x >> 16) & 1u)) >> 16);
}
__device__ __forceinline__ u32 pk2(float a, float b) {
    __hip_bfloat162 h = __float22bfloat162_rn(make_float2(a, b));
    return *reinterpret_cast<u32*>(&h);
}
__device__ __forceinline__ f32x4 max4(f32x4 a, f32x4 b) {
    return (f32x4){fmaxf(a[0], b[0]), fmaxf(a[1], b[1]),
                   fmaxf(a[2], b[2]), fmaxf(a[3], b[3])};
}
__device__ __forceinline__ f32x4 shfl_xor4(f32x4 v, int mask) {
    return (f32x4){__shfl_xor(v[0], mask), __shfl_xor(v[1], mask),
                   __shfl_xor(v[2], mask), __shfl_xor(v[3], mask)};
}

// ---------------------------------------------------------------------------
// transpose_w: W fp32 [K][Ntot] -> WT bf16 [ncols][K] (ncols starting nbase).
// 64x64 LDS tile; coalesced 16B loads and 32B stores. Ts stride 66 breaks
// the n-step-16 bank degeneracy (16*33 % 32 = 16).
// ---------------------------------------------------------------------------
__global__ __launch_bounds__(256, 2) void transpose_w_kernel(
    const float* __restrict__ W, u16* __restrict__ WT,
    int K, int Ntot, int nbase)
{
    __shared__ u16 Ts[64][66];
    const int t   = threadIdx.x;
    const int k0  = blockIdx.x * 64;
    const int n0l = blockIdx.y * 64;       // local col within WT
    const int n0g = nbase + n0l;           // global col in W

    {
        const int krow = t >> 2;           // 0..63
        const int nseg = (t & 3) * 16;     // 0,16,32,48
        const float* src = &W[(size_t)(k0 + krow) * Ntot + n0g + nseg];
        f32x4 v0 = reinterpret_cast<const f32x4*>(src)[0];
        f32x4 v1 = reinterpret_cast<const f32x4*>(src)[1];
        f32x4 v2 = reinterpret_cast<const f32x4*>(src)[2];
        f32x4 v3 = reinterpret_cast<const f32x4*>(src)[3];
        #pragma unroll
        for (int i = 0; i < 4; i++) Ts[nseg +      i][krow] = f2b(v0[i]);
        #pragma unroll
        for (int i = 0; i < 4; i++) Ts[nseg +  4 + i][krow] = f2b(v1[i]);
        #pragma unroll
        for (int i = 0; i < 4; i++) Ts[nseg +  8 + i][krow] = f2b(v2[i]);
        #pragma unroll
        for (int i = 0; i < 4; i++) Ts[nseg + 12 + i][krow] = f2b(v3[i]);
    }
    __syncthreads();
    {
        const int nrow = t >> 2;           // 0..63
        const int kseg = (t & 3) * 16;
        u32 out[8];
        #pragma unroll
        for (int c = 0; c < 8; c++)
            out[c] = (u32)Ts[nrow][kseg + 2 * c] | ((u32)Ts[nrow][kseg + 2 * c + 1] << 16);
        u16* dst = &WT[(size_t)(n0l + nrow) * K + k0 + kseg];
        *reinterpret_cast<u32x4*>(dst)     = (u32x4){out[0], out[1], out[2], out[3]};
        *reinterpret_cast<u32x4*>(dst + 8) = (u32x4){out[4], out[5], out[6], out[7]};
    }
}

// ---------------------------------------------------------------------------
// gemm_bt: C = A[M,K] @ B + bias, where BT is bf16 [ncols][K] (pre-transposed
// weight, cols offset ncol0 in the full N). Both operands staged with 16B
// vector loads (m93 structure). AF32: A fp32 (pk2-converted) else bf16.
// OUTMODE: 0 bf16 row-major, 1 fp32 row-major, 2 bf16 transposed VT[N][STOT]
// (coff = token offset).
// ---------------------------------------------------------------------------
template<int AF32, int OUTMODE>
__global__ __launch_bounds__(256, 2) void gemm_bt_kernel(
    const void* __restrict__ Av, const u16* __restrict__ BT,
    const float* __restrict__ bias, void* __restrict__ Cv, size_t coff,
    int M, int K, int Ntot, int ncol0)
{
    __shared__ u16 As[128][40];
    __shared__ u16 Bs[128][40];

    const int t    = threadIdx.x;
    const int lane = t & 63;
    const int wave = t >> 6;
    const int wr   = wave >> 1;
    const int wc   = wave & 1;
    const int m0   = blockIdx.x * 128;
    const int n0   = blockIdx.y * 128;   // local within BT
    const int fm   = lane & 15;
    const int fq   = lane >> 4;

    const int arow = t >> 1;
    const int akg  = (t & 1) * 16;

    f32x4 acc[4][4];
    #pragma unroll
    for (int i = 0; i < 4; i++)
        #pragma unroll
        for (int j = 0; j < 4; j++)
            acc[i][j] = (f32x4){0.f, 0.f, 0.f, 0.f};

    for (int k0 = 0; k0 < K; k0 += 32) {
        u32x4 a0, a1;
        if (AF32) {
            const f32x4* p = reinterpret_cast<const f32x4*>(
                (const float*)Av + (size_t)(m0 + arow) * K + k0 + akg);
            f32x4 x0 = p[0], x1 = p[1], x2 = p[2], x3 = p[3];
            a0 = (u32x4){pk2(x0[0], x0[1]), pk2(x0[2], x0[3]),
                         pk2(x1[0], x1[1]), pk2(x1[2], x1[3])};
            a1 = (u32x4){pk2(x2[0], x2[1]), pk2(x2[2], x2[3]),
                         pk2(x3[0], x3[1]), pk2(x3[2], x3[3])};
        } else {
            const u32x4* p = reinterpret_cast<const u32x4*>(
                (const u16*)Av + (size_t)(m0 + arow) * K + k0 + akg);
            a0 = p[0]; a1 = p[1];
        }
        const u32x4* bp = reinterpret_cast<const u32x4*>(
            &BT[(size_t)(n0 + arow) * K + k0 + akg]);
        u32x4 b0 = bp[0], b1 = bp[1];

        __syncthreads();
        *reinterpret_cast<u32x4*>(&As[arow][akg])     = a0;
        *reinterpret_cast<u32x4*>(&As[arow][akg + 8]) = a1;
        *reinterpret_cast<u32x4*>(&Bs[arow][akg])     = b0;
        *reinterpret_cast<u32x4*>(&Bs[arow][akg + 8]) = b1;
        __syncthreads();

        bf16x8 af[4], bfr[4];
        #pragma unroll
        for (int i = 0; i < 4; i++)
            af[i] = *reinterpret_cast<const bf16x8*>(&As[wr * 64 + i * 16 + fm][fq * 8]);
        #pragma unroll
        for (int j = 0; j < 4; j++)
            bfr[j] = *reinterpret_cast<const bf16x8*>(&Bs[wc * 64 + j * 16 + fm][fq * 8]);
        #pragma unroll
        for (int i = 0; i < 4; i++)
            #pragma unroll
            for (int j = 0; j < 4; j++)
                acc[i][j] = __builtin_amdgcn_mfma_f32_16x16x32_bf16(af[i], bfr[j], acc[i][j], 0, 0, 0);
    }

    #pragma unroll
    for (int i = 0; i < 4; i++) {
        #pragma unroll
        for (int j = 0; j < 4; j++) {
            int col = ncol0 + n0 + wc * 64 + j * 16 + fm;
            float bb = bias[col];
            if (OUTMODE == 2) {
                int tok = (int)coff + m0 + wr * 64 + i * 16 + fq * 4;
                u32x2 pr = {pk2(acc[i][j][0] + bb, acc[i][j][1] + bb),
                            pk2(acc[i][j][2] + bb, acc[i][j][3] + bb)};
                *reinterpret_cast<u32x2*>(&((u16*)Cv)[(size_t)col * STOT + tok]) = pr;
            } else {
                #pragma unroll
                for (int r = 0; r < 4; r++) {
                    int row = m0 + wr * 64 + i * 16 + fq * 4 + r;
                    size_t idx = coff + (size_t)row * Ntot + col;
                    float val = acc[i][j][r] + bb;
                    if (OUTMODE == 1) ((float*)Cv)[idx] = val;
                    else              ((u16*)Cv)[idx]   = f2b(val);
                }
            }
        }
    }
}

// ---------------------------------------------------------------------------
// Fallback GEMM (fp32 W, scalar staging) — used only if ws_size is too small
// for the WT scratch buffer.
// ---------------------------------------------------------------------------
template<int AF32, int OUTMODE>
__global__ __launch_bounds__(256, 2) void gemm_bias_kernel(
    const void* __restrict__ Av, const float* __restrict__ W,
    const float* __restrict__ bias, void* __restrict__ Cv, size_t coff,
    int M, int K, int N)
{
    __shared__ u16 As[128][40];
    __shared__ u16 Bs[128][40];

    const int t    = threadIdx.x;
    const int lane = t & 63;
    const int wave = t >> 6;
    const int wr   = wave >> 1;
    const int wc   = wave & 1;
    const int m0   = blockIdx.x * 128;
    const int n0   = blockIdx.y * 128;
    const int fm   = lane & 15;
    const int fq   = lane >> 4;

    const int arow = t >> 1;
    const int akg  = (t & 1) * 16;
    const int bn   = t >> 1;
    const int bkg  = (t & 1) * 16;

    f32x4 acc[4][4];
    #pragma unroll
    for (int i = 0; i < 4; i++)
        #pragma unroll
        for (int j = 0; j < 4; j++)
            acc[i][j] = (f32x4){0.f, 0.f, 0.f, 0.f};

    for (int k0 = 0; k0 < K; k0 += 32) {
        u32x4 a0, a1;
        if (AF32) {
            const f32x4* p = reinterpret_cast<const f32x4*>(
                (const float*)Av + (size_t)(m0 + arow) * K + k0 + akg);
            f32x4 x0 = p[0], x1 = p[1], x2 = p[2], x3 = p[3];
            a0 = (u32x4){pk2(x0[0], x0[1]), pk2(x0[2], x0[3]),
                         pk2(x1[0], x1[1]), pk2(x1[2], x1[3])};
            a1 = (u32x4){pk2(x2[0], x2[1]), pk2(x2[2], x2[3]),
                         pk2(x3[0], x3[1]), pk2(x3[2], x3[3])};
        } else {
            const u32x4* p = reinterpret_cast<const u32x4*>(
                (const u16*)Av + (size_t)(m0 + arow) * K + k0 + akg);
            a0 = p[0]; a1 = p[1];
        }
        float wv[16];
        #pragma unroll
        for (int j = 0; j < 16; j++)
            wv[j] = W[(size_t)(k0 + bkg + j) * N + n0 + bn];
        u32x4 b0, b1;
        #pragma unroll
        for (int j = 0; j < 4; j++) {
            b0[j] = pk2(wv[2 * j],     wv[2 * j + 1]);
            b1[j] = pk2(wv[8 + 2 * j], wv[8 + 2 * j + 1]);
        }
        __syncthreads();
        *reinterpret_cast<u32x4*>(&As[arow][akg])     = a0;
        *reinterpret_cast<u32x4*>(&As[arow][akg + 8]) = a1;
        *reinterpret_cast<u32x4*>(&Bs[bn][bkg])       = b0;
        *reinterpret_cast<u32x4*>(&Bs[bn][bkg + 8])   = b1;
        __syncthreads();

        bf16x8 af[4], bfr[4];
        #pragma unroll
        for (int i = 0; i < 4; i++)
            af[i] = *reinterpret_cast<const bf16x8*>(&As[wr * 64 + i * 16 + fm][fq * 8]);
        #pragma unroll
        for (int j = 0; j < 4; j++)
            bfr[j] = *reinterpret_cast<const bf16x8*>(&Bs[wc * 64 + j * 16 + fm][fq * 8]);
        #pragma unroll
        for (int i = 0; i < 4; i++)
            #pragma unroll
            for (int j = 0; j < 4; j++)
                acc[i][j] = __builtin_amdgcn_mfma_f32_16x16x32_bf16(af[i], bfr[j], acc[i][j], 0, 0, 0);
    }

    #pragma unroll
    for (int i = 0; i < 4; i++) {
        #pragma unroll
        for (int j = 0; j < 4; j++) {
            int col = n0 + wc * 64 + j * 16 + fm;
            float bb = bias[col];
            if (OUTMODE == 2) {
                int tok = (int)coff + m0 + wr * 64 + i * 16 + fq * 4;
                u32x2 pr = {pk2(acc[i][j][0] + bb, acc[i][j][1] + bb),
                            pk2(acc[i][j][2] + bb, acc[i][j][3] + bb)};
                *reinterpret_cast<u32x2*>(&((u16*)Cv)[(size_t)col * STOT + tok]) = pr;
            } else {
                #pragma unroll
                for (int r = 0; r < 4; r++) {
                    int row = m0 + wr * 64 + i * 16 + fq * 4 + r;
                    size_t idx = coff + (size_t)row * N + col;
                    float val = acc[i][j][r] + bb;
                    if (OUTMODE == 1) ((float*)Cv)[idx] = val;
                    else              ((u16*)Cv)[idx]   = f2b(val);
                }
            }
        }
    }
}

// ---------------------------------------------------------------------------
// Fused per-head RMSNorm + interleaved RoPE, in place on bf16 Q/K buffers.
// ---------------------------------------------------------------------------
__global__ __launch_bounds__(64) void rmsrope_kernel(
    u16* __restrict__ Qf, u16* __restrict__ Kf,
    const float* __restrict__ nq, const float* __restrict__ nk,
    const float* __restrict__ naq, const float* __restrict__ nak,
    const float* __restrict__ cosb, const float* __restrict__ sinb)
{
    const int h     = blockIdx.x;
    const int tok   = blockIdx.y;
    const int which = blockIdx.z;
    u16* buf = which ? Kf : Qf;
    const float* nw = (tok < TXT) ? (which ? nak : naq) : (which ? nk : nq);
    const int t = threadIdx.x;
    const size_t base = (size_t)tok * DIM + h * HD + 2 * t;

    u32 pr = *reinterpret_cast<const u32*>(&buf[base]);
    float x0 = b2f((u16)(pr & 0xFFFF));
    float x1 = b2f((u16)(pr >> 16));

    float ss = x0 * x0 + x1 * x1;
    #pragma unroll
    for (int off = 32; off; off >>= 1) ss += __shfl_xor(ss, off);
    float r = rsqrtf(ss * (1.0f / 128.0f) + 1e-6f);

    float y0 = x0 * r * nw[2 * t];
    float y1 = x1 * r * nw[2 * t + 1];
    float c0 = cosb[tok * HD + 2 * t];
    float c1 = cosb[tok * HD + 2 * t + 1];
    float s0 = sinb[tok * HD + 2 * t];
    float s1 = sinb[tok * HD + 2 * t + 1];
    float o0 = y0 * c0 - y1 * s0;
    float o1 = y1 * c1 + y0 * s1;
    *reinterpret_cast<u32*>(&buf[base]) = pk2(o0, o1);
}

// ---------------------------------------------------------------------------
// MFMA flash attention (unchanged from R5 — verified).
// ---------------------------------------------------------------------------
__global__ __launch_bounds__(256, 2) void attn_kernel(
    const u16* __restrict__ Qf, const u16* __restrict__ Kf,
    const u16* __restrict__ VTg, u16* __restrict__ AO)
{
    __shared__ u16 Ks[64][136];
    __shared__ u16 VTs[128][72];
    __shared__ u16 Ps[4][16][72];

    const int t    = threadIdx.x;
    const int w    = t >> 6;
    const int lane = t & 63;
    const int col  = lane & 15;
    const int quad = lane >> 4;
    const int h    = blockIdx.y;
    const int q0   = blockIdx.x * 64;
    const bool is_ref = (q0 >= TXT) && (q0 < TXT + 512);
    const int ks = is_ref ? TXT : 0;
    const int ke = is_ref ? (TXT + 512) : STOT;

    const size_t qbase = (size_t)(q0 + w * 16 + col) * DIM + h * HD;
    bf16x8 Qfrag[4];
    #pragma unroll
    for (int c = 0; c < 4; c++)
        Qfrag[c] = *reinterpret_cast<const bf16x8*>(&Qf[qbase + c * 32 + quad * 8]);

    f32x4 O[8];
    #pragma unroll
    for (int dt = 0; dt < 8; dt++) O[dt] = (f32x4){0.f, 0.f, 0.f, 0.f};
    f32x4 m = (f32x4){-1e30f, -1e30f, -1e30f, -1e30f};
    f32x4 l = (f32x4){0.f, 0.f, 0.f, 0.f};

    const int krow = t >> 2, kseg = t & 3;
    const int vrow = t >> 1, vseg = t & 1;

    for (int k0 = ks; k0 < ke; k0 += 64) {
        __syncthreads();
        {
            const u32x4* src = reinterpret_cast<const u32x4*>(
                &Kf[(size_t)(k0 + krow) * DIM + h * HD + kseg * 32]);
            u32x4 v0 = src[0], v1 = src[1], v2 = src[2], v3 = src[3];
            u32x4* dst = reinterpret_cast<u32x4*>(&Ks[krow][kseg * 32]);
            dst[0] = v0; dst[1] = v1; dst[2] = v2; dst[3] = v3;
        }
        {
            const u32x4* src = reinterpret_cast<const u32x4*>(
                &VTg[(size_t)(h * HD + vrow) * STOT + k0 + vseg * 32]);
            u32x4 v0 = src[0], v1 = src[1], v2 = src[2], v3 = src[3];
            u32x4* dst = reinterpret_cast<u32x4*>(&VTs[vrow][vseg * 32]);
            dst[0] = v0; dst[1] = v1; dst[2] = v2; dst[3] = v3;
        }
        __syncthreads();

        f32x4 s[4];
        #pragma unroll
        for (int kt = 0; kt < 4; kt++) {
            f32x4 a = (f32x4){0.f, 0.f, 0.f, 0.f};
            #pragma unroll
            for (int c = 0; c < 4; c++) {
                bf16x8 kf = *reinterpret_cast<const bf16x8*>(
                    &Ks[kt * 16 + col][c * 32 + quad * 8]);
                a = __builtin_amdgcn_mfma_f32_16x16x32_bf16(Qfrag[c], kf, a, 0, 0, 0);
            }
            s[kt] = a * SOFTMAX_SCALE;
        }

        f32x4 tmax = max4(max4(s[0], s[1]), max4(s[2], s[3]));
        tmax = max4(tmax, shfl_xor4(tmax, 1));
        tmax = max4(tmax, shfl_xor4(tmax, 2));
        tmax = max4(tmax, shfl_xor4(tmax, 4));
        tmax = max4(tmax, shfl_xor4(tmax, 8));
        f32x4 mnew = max4(m, tmax);
        f32x4 alpha, rowsum = (f32x4){0.f, 0.f, 0.f, 0.f};
        #pragma unroll
        for (int r = 0; r < 4; r++) alpha[r] = __expf(m[r] - mnew[r]);
        f32x4 p[4];
        #pragma unroll
        for (int kt = 0; kt < 4; kt++)
            #pragma unroll
            for (int r = 0; r < 4; r++) {
                p[kt][r] = __expf(s[kt][r] - mnew[r]);
                rowsum[r] += p[kt][r];
            }
        rowsum += shfl_xor4(rowsum, 1);
        rowsum += shfl_xor4(rowsum, 2);
        rowsum += shfl_xor4(rowsum, 4);
        rowsum += shfl_xor4(rowsum, 8);
        #pragma unroll
        for (int r = 0; r < 4; r++) l[r] = l[r] * alpha[r] + rowsum[r];
        m = mnew;
        #pragma unroll
        for (int dt = 0; dt < 8; dt++)
            #pragma unroll
            for (int r = 0; r < 4; r++) O[dt][r] *= alpha[r];

        #pragma unroll
        for (int kt = 0; kt < 4; kt++)
            #pragma unroll
            for (int r = 0; r < 4; r++)
                Ps[w][quad * 4 + r][kt * 16 + col] = f2b(p[kt][r]);

        #pragma unroll
        for (int c = 0; c < 2; c++) {
            bf16x8 pf = *reinterpret_cast<const bf16x8*>(
                &Ps[w][col][c * 32 + quad * 8]);
            #pragma unroll
            for (int dt = 0; dt < 8; dt++) {
                bf16x8 vf = *reinterpret_cast<const bf16x8*>(
                    &VTs[dt * 16 + col][c * 32 + quad * 8]);
                O[dt] = __builtin_amdgcn_mfma_f32_16x16x32_bf16(pf, vf, O[dt], 0, 0, 0);
            }
        }
    }

    f32x4 inv;
    #pragma unroll
    for (int r = 0; r < 4; r++) inv[r] = 1.0f / l[r];
    #pragma unroll
    for (int dt = 0; dt < 8; dt++)
        #pragma unroll
        for (int r = 0; r < 4; r++)
            AO[(size_t)(q0 + w * 16 + quad * 4 + r) * DIM + h * HD + dt * 16 + col] =
                f2b(O[dt][r] * inv[r]);
}

// ---------------------------------------------------------------------------
// Buffer plan:
//   Qf/AO = d_ws            [STOT*DIM bf16] 15.7 MB
//   WT    = d_ws + 15.7 MB  [up to DIM*DIM bf16] (tiered on ws_size)
//   Kf    = d_out lower     [STOT*DIM bf16]
//   VTg   = d_out upper     [DIM][STOT] bf16
// ---------------------------------------------------------------------------
extern "C" void kernel_launch(void* const* d_in, const int* in_sizes, int n_in,
                              void* d_out, int out_size, void* d_ws, size_t ws_size,
                              hipStream_t stream)
{
    const void*  hs  = d_in[0];
    const void*  enc = d_in[1];
    const float* rc  = (const float*)d_in[2];
    const float* rs  = (const float*)d_in[3];
    const float* wq  = (const float*)d_in[4];  const float* bq  = (const float*)d_in[5];
    const float* wk  = (const float*)d_in[6];  const float* bk  = (const float*)d_in[7];
    const float* wv  = (const float*)d_in[8];  const float* bv  = (const float*)d_in[9];
    const float* waq = (const float*)d_in[10]; const float* baq = (const float*)d_in[11];
    const float* wak = (const float*)d_in[12]; const float* bak = (const float*)d_in[13];
    const float* wav = (const float*)d_in[14]; const float* bav = (const float*)d_in[15];
    const float* nq  = (const float*)d_in[16]; const float* nk  = (const float*)d_in[17];
    const float* naq = (const float*)d_in[18]; const float* nak = (const float*)d_in[19];
    const float* wo  = (const float*)d_in[20]; const float* bo  = (const float*)d_in[21];
    const float* wao = (const float*)d_in[22]; const float* bao = (const float*)d_in[23];

    const size_t QFB = (size_t)STOT * DIM * sizeof(u16);      // 15,728,640
    const size_t WTF = (size_t)DIM * DIM * sizeof(u16);       // 18,874,368
    u16* Qf  = (u16*)d_ws;
    u16* WT  = (u16*)((char*)d_ws + QFB);
    u16* Kf  = (u16*)d_out;
    u16* VTg = (u16*)d_out + (size_t)STOT * DIM;
    u16* AO  = Qf;

    dim3 blk(256);

    // choose N-chunk per available workspace (deterministic per process)
    int nchunk;
    if      (ws_size >= QFB + WTF)     nchunk = DIM;
    else if (ws_size >= QFB + WTF / 2) nchunk = DIM / 2;
    else                               nchunk = 0;   // fallback path

    if (nchunk > 0) {
        dim3 tgrid(DIM / 64, nchunk / 64);
        // helper macro: transpose W-chunk then run gemm_bt over that chunk
        #define RUN_GEMM(AF32_, MODE_, Aptr, Wptr, Bias, Cptr, Coff, M_)          \
            for (int nb = 0; nb < DIM; nb += nchunk) {                            \
                transpose_w_kernel<<<tgrid, blk, 0, stream>>>(Wptr, WT, DIM, DIM, nb); \
                gemm_bt_kernel<AF32_, MODE_><<<dim3((M_) / 128, nchunk / 128), blk, 0, stream>>>( \
                    Aptr, WT, Bias, Cptr, Coff, M_, DIM, DIM, nb);                \
            }
        RUN_GEMM(1, 0, hs,  wq,  bq,  Qf,  (size_t)TXT * DIM, SEQ)
        RUN_GEMM(1, 0, hs,  wk,  bk,  Kf,  (size_t)TXT * DIM, SEQ)
        RUN_GEMM(1, 2, hs,  wv,  bv,  VTg, (size_t)TXT,       SEQ)
        RUN_GEMM(1, 0, enc, waq, baq, Qf,  0,                 TXT)
        RUN_GEMM(1, 0, enc, wak, bak, Kf,  0,                 TXT)
        RUN_GEMM(1, 2, enc, wav, bav, VTg, 0,                 TXT)
        rmsrope_kernel<<<dim3(NH, STOT, 2), dim3(64), 0, stream>>>(Qf, Kf, nq, nk, naq, nak, rc, rs);
        attn_kernel<<<dim3(STOT / 64, NH), blk, 0, stream>>>(Qf, Kf, VTg, AO);
        RUN_GEMM(0, 1, AO + (size_t)TXT * DIM, wo,  bo,  d_out, 0,                 SEQ)
        RUN_GEMM(0, 1, AO,                     wao, bao, d_out, (size_t)SEQ * DIM, TXT)
        #undef RUN_GEMM
    } else {
        // fallback: fp32-W scalar staging (R5 path)
        gemm_bias_kernel<1,0><<<dim3(SEQ / 128, DIM / 128), blk, 0, stream>>>(hs, wq, bq, Qf, (size_t)TXT * DIM, SEQ, DIM, DIM);
        gemm_bias_kernel<1,0><<<dim3(SEQ / 128, DIM / 128), blk, 0, stream>>>(hs, wk, bk, Kf, (size_t)TXT * DIM, SEQ, DIM, DIM);
        gemm_bias_kernel<1,2><<<dim3(SEQ / 128, DIM / 128), blk, 0, stream>>>(hs, wv, bv, VTg, (size_t)TXT, SEQ, DIM, DIM);
        gemm_bias_kernel<1,0><<<dim3(TXT / 128, DIM / 128), blk, 0, stream>>>(enc, waq, baq, Qf, 0, TXT, DIM, DIM);
        gemm_bias_kernel<1,0><<<dim3(TXT / 128, DIM / 128), blk, 0, stream>>>(enc, wak, bak, Kf, 0, TXT, DIM, DIM);
        gemm_bias_kernel<1,2><<<dim3(TXT / 128, DIM / 128), blk, 0, stream>>>(enc, wav, bav, VTg, 0, TXT, DIM, DIM);
        rmsrope_kernel<<<dim3(NH, STOT, 2), dim3(64), 0, stream>>>(Qf, Kf, nq, nk, naq, nak, rc, rs);
        attn_kernel<<<dim3(STOT / 64, NH), blk, 0, stream>>>(Qf, Kf, VTg, AO);
        gemm_bias_kernel<0,1><<<dim3(SEQ / 128, DIM / 128), blk, 0, stream>>>(AO + (size_t)TXT * DIM, wo, bo, d_out, 0, SEQ, DIM, DIM);
        gemm_bias_kernel<0,1><<<dim3(TXT / 128, DIM / 128), blk, 0, stream>>>(AO, wao, bao, d_out, (size_t)SEQ * DIM, TXT, DIM, DIM);
    }
}

// Round 7
// 1306.768 us; speedup vs baseline: 2.9154x; 1.0470x over previous
//
#include <hip/hip_runtime.h>
#include <hip/hip_bf16.h>

typedef unsigned short u16;
typedef unsigned int u32;
typedef __bf16 bf16x8 __attribute__((ext_vector_type(8)));
typedef float f32x4 __attribute__((ext_vector_type(4)));
typedef unsigned int u32x4 __attribute__((ext_vector_type(4)));
typedef unsigned int u32x2 __attribute__((ext_vector_type(2)));

#define TXT 512
#define SEQ 2048
#define STOT 2560
#define DIM 3072
#define NH 24
#define HD 128
#define SOFTMAX_SCALE 0.08838834764831845f

__device__ __forceinline__ float b2f(u16 u) {
    union { u32 i; float f; } c; c.i = ((u32)u) << 16; return c.f;
}
__device__ __forceinline__ u16 f2b(float f) {
    union { float f; u32 i; } c; c.f = f;
    u32 x = c.i;
    return (u16)((x + 0x7FFFu + ((x >> 16) & 1u)) >> 16);
}
__device__ __forceinline__ u32 pk2(float a, float b) {
    __hip_bfloat162 h = __float22bfloat162_rn(make_float2(a, b));
    return *reinterpret_cast<u32*>(&h);
}
__device__ __forceinline__ f32x4 max4(f32x4 a, f32x4 b) {
    return (f32x4){fmaxf(a[0], b[0]), fmaxf(a[1], b[1]),
                   fmaxf(a[2], b[2]), fmaxf(a[3], b[3])};
}
__device__ __forceinline__ f32x4 shfl_xor4(f32x4 v, int mask) {
    return (f32x4){__shfl_xor(v[0], mask), __shfl_xor(v[1], mask),
                   __shfl_xor(v[2], mask), __shfl_xor(v[3], mask)};
}

// ---------------------------------------------------------------------------
// transpose_w: W fp32 [K][Ntot] -> WT bf16 [ncols][K] (ncols from nbase).
// ---------------------------------------------------------------------------
__global__ __launch_bounds__(256, 2) void transpose_w_kernel(
    const float* __restrict__ W, u16* __restrict__ WT,
    int K, int Ntot, int nbase)
{
    __shared__ u16 Ts[64][66];
    const int t   = threadIdx.x;
    const int k0  = blockIdx.x * 64;
    const int n0l = blockIdx.y * 64;
    const int n0g = nbase + n0l;

    {
        const int krow = t >> 2;
        const int nseg = (t & 3) * 16;
        const float* src = &W[(size_t)(k0 + krow) * Ntot + n0g + nseg];
        f32x4 v0 = reinterpret_cast<const f32x4*>(src)[0];
        f32x4 v1 = reinterpret_cast<const f32x4*>(src)[1];
        f32x4 v2 = reinterpret_cast<const f32x4*>(src)[2];
        f32x4 v3 = reinterpret_cast<const f32x4*>(src)[3];
        #pragma unroll
        for (int i = 0; i < 4; i++) Ts[nseg +      i][krow] = f2b(v0[i]);
        #pragma unroll
        for (int i = 0; i < 4; i++) Ts[nseg +  4 + i][krow] = f2b(v1[i]);
        #pragma unroll
        for (int i = 0; i < 4; i++) Ts[nseg +  8 + i][krow] = f2b(v2[i]);
        #pragma unroll
        for (int i = 0; i < 4; i++) Ts[nseg + 12 + i][krow] = f2b(v3[i]);
    }
    __syncthreads();
    {
        const int nrow = t >> 2;
        const int kseg = (t & 3) * 16;
        u32 out[8];
        #pragma unroll
        for (int c = 0; c < 8; c++)
            out[c] = (u32)Ts[nrow][kseg + 2 * c] | ((u32)Ts[nrow][kseg + 2 * c + 1] << 16);
        u16* dst = &WT[(size_t)(n0l + nrow) * K + k0 + kseg];
        *reinterpret_cast<u32x4*>(dst)     = (u32x4){out[0], out[1], out[2], out[3]};
        *reinterpret_cast<u32x4*>(dst + 8) = (u32x4){out[4], out[5], out[6], out[7]};
    }
}

// ---------------------------------------------------------------------------
// gemm_bt: C = A[M,K] @ B + bias, BT bf16 [ncols][K] pre-transposed.
// BK=64 (32 MFMA between barriers). MT = M-tile (128 or 64; 64 doubles the
// grid for M=512 shapes -> better CU coverage). 4 waves as 2x2; wave tile
// (MT/2) x 64. AF32: A fp32 (pk2-converted) else bf16.
// OUTMODE: 0 bf16 row-major, 1 fp32 row-major, 2 bf16 transposed VT[N][STOT].
// ---------------------------------------------------------------------------
template<int AF32, int OUTMODE, int MT>
__global__ __launch_bounds__(256, 2) void gemm_bt_kernel(
    const void* __restrict__ Av, const u16* __restrict__ BT,
    const float* __restrict__ bias, void* __restrict__ Cv, size_t coff,
    int M, int K, int Ntot, int ncol0)
{
    constexpr int MI = MT / 32;            // acc row-tiles per wave
    constexpr int ASEGN = (MT == 128) ? 32 : 16;  // A k-elems staged/thread
    __shared__ u16 As[MT][72];             // [m][k], +8 pad
    __shared__ u16 Bs[128][72];            // [n][k], +8 pad

    const int t    = threadIdx.x;
    const int lane = t & 63;
    const int wave = t >> 6;
    const int wr   = wave >> 1;
    const int wc   = wave & 1;
    const int m0   = blockIdx.x * MT;
    const int n0   = blockIdx.y * 128;
    const int fm   = lane & 15;
    const int fq   = lane >> 4;

    const int arow = (MT == 128) ? (t >> 1) : (t >> 2);
    const int aseg = (MT == 128) ? ((t & 1) * 32) : ((t & 3) * 16);
    const int brow = t >> 1;
    const int bseg = (t & 1) * 32;

    f32x4 acc[MI][4];
    #pragma unroll
    for (int i = 0; i < MI; i++)
        #pragma unroll
        for (int j = 0; j < 4; j++)
            acc[i][j] = (f32x4){0.f, 0.f, 0.f, 0.f};

    for (int k0 = 0; k0 < K; k0 += 64) {
        // ---- A fragment: ASEGN consecutive k ----
        u32 aw[ASEGN / 2];
        if (AF32) {
            const float* ap = (const float*)Av + (size_t)(m0 + arow) * K + k0 + aseg;
            #pragma unroll
            for (int c = 0; c < ASEGN / 4; c++) {
                f32x4 x = reinterpret_cast<const f32x4*>(ap)[c];
                aw[2 * c]     = pk2(x[0], x[1]);
                aw[2 * c + 1] = pk2(x[2], x[3]);
            }
        } else {
            const u32x4* ap = reinterpret_cast<const u32x4*>(
                (const u16*)Av + (size_t)(m0 + arow) * K + k0 + aseg);
            #pragma unroll
            for (int c = 0; c < ASEGN / 8; c++) {
                u32x4 x = ap[c];
                aw[4 * c] = x[0]; aw[4 * c + 1] = x[1];
                aw[4 * c + 2] = x[2]; aw[4 * c + 3] = x[3];
            }
        }
        // ---- B fragment: 32 consecutive k (64 B) ----
        u32x4 bw[4];
        {
            const u32x4* bp = reinterpret_cast<const u32x4*>(
                &BT[(size_t)(n0 + brow) * K + k0 + bseg]);
            bw[0] = bp[0]; bw[1] = bp[1]; bw[2] = bp[2]; bw[3] = bp[3];
        }
        __syncthreads();   // prior iteration's LDS reads complete
        #pragma unroll
        for (int c = 0; c < ASEGN / 8; c++)
            *reinterpret_cast<u32x4*>(&As[arow][aseg + c * 8]) =
                (u32x4){aw[4 * c], aw[4 * c + 1], aw[4 * c + 2], aw[4 * c + 3]};
        #pragma unroll
        for (int c = 0; c < 4; c++)
            *reinterpret_cast<u32x4*>(&Bs[brow][bseg + c * 8]) = bw[c];
        __syncthreads();

        #pragma unroll
        for (int h = 0; h < 2; h++) {
            bf16x8 af[MI], bfr[4];
            #pragma unroll
            for (int i = 0; i < MI; i++)
                af[i] = *reinterpret_cast<const bf16x8*>(
                    &As[wr * (MT / 2) + i * 16 + fm][h * 32 + fq * 8]);
            #pragma unroll
            for (int j = 0; j < 4; j++)
                bfr[j] = *reinterpret_cast<const bf16x8*>(
                    &Bs[wc * 64 + j * 16 + fm][h * 32 + fq * 8]);
            #pragma unroll
            for (int i = 0; i < MI; i++)
                #pragma unroll
                for (int j = 0; j < 4; j++)
                    acc[i][j] = __builtin_amdgcn_mfma_f32_16x16x32_bf16(af[i], bfr[j], acc[i][j], 0, 0, 0);
        }
    }

    // epilogue: C/D layout col = lane&15, row = (lane>>4)*4 + r
    #pragma unroll
    for (int i = 0; i < MI; i++) {
        #pragma unroll
        for (int j = 0; j < 4; j++) {
            int col = ncol0 + n0 + wc * 64 + j * 16 + fm;
            float bb = bias[col];
            if (OUTMODE == 2) {
                int tok = (int)coff + m0 + wr * (MT / 2) + i * 16 + fq * 4;
                u32x2 pr = {pk2(acc[i][j][0] + bb, acc[i][j][1] + bb),
                            pk2(acc[i][j][2] + bb, acc[i][j][3] + bb)};
                *reinterpret_cast<u32x2*>(&((u16*)Cv)[(size_t)col * STOT + tok]) = pr;
            } else {
                #pragma unroll
                for (int r = 0; r < 4; r++) {
                    int row = m0 + wr * (MT / 2) + i * 16 + fq * 4 + r;
                    size_t idx = coff + (size_t)row * Ntot + col;
                    float val = acc[i][j][r] + bb;
                    if (OUTMODE == 1) ((float*)Cv)[idx] = val;
                    else              ((u16*)Cv)[idx]   = f2b(val);
                }
            }
        }
    }
}

// ---------------------------------------------------------------------------
// Fallback GEMM (fp32 W, scalar staging, BK=32) — only if ws too small.
// ---------------------------------------------------------------------------
template<int AF32, int OUTMODE>
__global__ __launch_bounds__(256, 2) void gemm_bias_kernel(
    const void* __restrict__ Av, const float* __restrict__ W,
    const float* __restrict__ bias, void* __restrict__ Cv, size_t coff,
    int M, int K, int N)
{
    __shared__ u16 As[128][40];
    __shared__ u16 Bs[128][40];

    const int t    = threadIdx.x;
    const int lane = t & 63;
    const int wave = t >> 6;
    const int wr   = wave >> 1;
    const int wc   = wave & 1;
    const int m0   = blockIdx.x * 128;
    const int n0   = blockIdx.y * 128;
    const int fm   = lane & 15;
    const int fq   = lane >> 4;

    const int arow = t >> 1;
    const int akg  = (t & 1) * 16;
    const int bn   = t >> 1;
    const int bkg  = (t & 1) * 16;

    f32x4 acc[4][4];
    #pragma unroll
    for (int i = 0; i < 4; i++)
        #pragma unroll
        for (int j = 0; j < 4; j++)
            acc[i][j] = (f32x4){0.f, 0.f, 0.f, 0.f};

    for (int k0 = 0; k0 < K; k0 += 32) {
        u32x4 a0, a1;
        if (AF32) {
            const f32x4* p = reinterpret_cast<const f32x4*>(
                (const float*)Av + (size_t)(m0 + arow) * K + k0 + akg);
            f32x4 x0 = p[0], x1 = p[1], x2 = p[2], x3 = p[3];
            a0 = (u32x4){pk2(x0[0], x0[1]), pk2(x0[2], x0[3]),
                         pk2(x1[0], x1[1]), pk2(x1[2], x1[3])};
            a1 = (u32x4){pk2(x2[0], x2[1]), pk2(x2[2], x2[3]),
                         pk2(x3[0], x3[1]), pk2(x3[2], x3[3])};
        } else {
            const u32x4* p = reinterpret_cast<const u32x4*>(
                (const u16*)Av + (size_t)(m0 + arow) * K + k0 + akg);
            a0 = p[0]; a1 = p[1];
        }
        float wv[16];
        #pragma unroll
        for (int j = 0; j < 16; j++)
            wv[j] = W[(size_t)(k0 + bkg + j) * N + n0 + bn];
        u32x4 b0, b1;
        #pragma unroll
        for (int j = 0; j < 4; j++) {
            b0[j] = pk2(wv[2 * j],     wv[2 * j + 1]);
            b1[j] = pk2(wv[8 + 2 * j], wv[8 + 2 * j + 1]);
        }
        __syncthreads();
        *reinterpret_cast<u32x4*>(&As[arow][akg])     = a0;
        *reinterpret_cast<u32x4*>(&As[arow][akg + 8]) = a1;
        *reinterpret_cast<u32x4*>(&Bs[bn][bkg])       = b0;
        *reinterpret_cast<u32x4*>(&Bs[bn][bkg + 8])   = b1;
        __syncthreads();

        bf16x8 af[4], bfr[4];
        #pragma unroll
        for (int i = 0; i < 4; i++)
            af[i] = *reinterpret_cast<const bf16x8*>(&As[wr * 64 + i * 16 + fm][fq * 8]);
        #pragma unroll
        for (int j = 0; j < 4; j++)
            bfr[j] = *reinterpret_cast<const bf16x8*>(&Bs[wc * 64 + j * 16 + fm][fq * 8]);
        #pragma unroll
        for (int i = 0; i < 4; i++)
            #pragma unroll
            for (int j = 0; j < 4; j++)
                acc[i][j] = __builtin_amdgcn_mfma_f32_16x16x32_bf16(af[i], bfr[j], acc[i][j], 0, 0, 0);
    }

    #pragma unroll
    for (int i = 0; i < 4; i++) {
        #pragma unroll
        for (int j = 0; j < 4; j++) {
            int col = n0 + wc * 64 + j * 16 + fm;
            float bb = bias[col];
            if (OUTMODE == 2) {
                int tok = (int)coff + m0 + wr * 64 + i * 16 + fq * 4;
                u32x2 pr = {pk2(acc[i][j][0] + bb, acc[i][j][1] + bb),
                            pk2(acc[i][j][2] + bb, acc[i][j][3] + bb)};
                *reinterpret_cast<u32x2*>(&((u16*)Cv)[(size_t)col * STOT + tok]) = pr;
            } else {
                #pragma unroll
                for (int r = 0; r < 4; r++) {
                    int row = m0 + wr * 64 + i * 16 + fq * 4 + r;
                    size_t idx = coff + (size_t)row * N + col;
                    float val = acc[i][j][r] + bb;
                    if (OUTMODE == 1) ((float*)Cv)[idx] = val;
                    else              ((u16*)Cv)[idx]   = f2b(val);
                }
            }
        }
    }
}

// ---------------------------------------------------------------------------
// Fused per-head RMSNorm + RoPE, in place. 4 waves/block, one token each.
// ---------------------------------------------------------------------------
__global__ __launch_bounds__(256) void rmsrope_kernel(
    u16* __restrict__ Qf, u16* __restrict__ Kf,
    const float* __restrict__ nq, const float* __restrict__ nk,
    const float* __restrict__ naq, const float* __restrict__ nak,
    const float* __restrict__ cosb, const float* __restrict__ sinb)
{
    const int h     = blockIdx.x;
    const int tok   = blockIdx.y * 4 + (threadIdx.x >> 6);
    const int which = blockIdx.z;
    u16* buf = which ? Kf : Qf;
    const float* nw = (tok < TXT) ? (which ? nak : naq) : (which ? nk : nq);
    const int t = threadIdx.x & 63;
    const size_t base = (size_t)tok * DIM + h * HD + 2 * t;

    u32 pr = *reinterpret_cast<const u32*>(&buf[base]);
    float x0 = b2f((u16)(pr & 0xFFFF));
    float x1 = b2f((u16)(pr >> 16));

    float ss = x0 * x0 + x1 * x1;
    #pragma unroll
    for (int off = 32; off; off >>= 1) ss += __shfl_xor(ss, off);
    float r = rsqrtf(ss * (1.0f / 128.0f) + 1e-6f);

    float y0 = x0 * r * nw[2 * t];
    float y1 = x1 * r * nw[2 * t + 1];
    float c0 = cosb[tok * HD + 2 * t];
    float c1 = cosb[tok * HD + 2 * t + 1];
    float s0 = sinb[tok * HD + 2 * t];
    float s1 = sinb[tok * HD + 2 * t + 1];
    float o0 = y0 * c0 - y1 * s0;
    float o1 = y1 * c1 + y0 * s1;
    *reinterpret_cast<u32*>(&buf[base]) = pk2(o0, o1);
}

// ---------------------------------------------------------------------------
// MFMA flash attention (verified R5 structure, unchanged).
// ---------------------------------------------------------------------------
__global__ __launch_bounds__(256, 2) void attn_kernel(
    const u16* __restrict__ Qf, const u16* __restrict__ Kf,
    const u16* __restrict__ VTg, u16* __restrict__ AO)
{
    __shared__ u16 Ks[64][136];
    __shared__ u16 VTs[128][72];
    __shared__ u16 Ps[4][16][72];

    const int t    = threadIdx.x;
    const int w    = t >> 6;
    const int lane = t & 63;
    const int col  = lane & 15;
    const int quad = lane >> 4;
    const int h    = blockIdx.y;
    const int q0   = blockIdx.x * 64;
    const bool is_ref = (q0 >= TXT) && (q0 < TXT + 512);
    const int ks = is_ref ? TXT : 0;
    const int ke = is_ref ? (TXT + 512) : STOT;

    const size_t qbase = (size_t)(q0 + w * 16 + col) * DIM + h * HD;
    bf16x8 Qfrag[4];
    #pragma unroll
    for (int c = 0; c < 4; c++)
        Qfrag[c] = *reinterpret_cast<const bf16x8*>(&Qf[qbase + c * 32 + quad * 8]);

    f32x4 O[8];
    #pragma unroll
    for (int dt = 0; dt < 8; dt++) O[dt] = (f32x4){0.f, 0.f, 0.f, 0.f};
    f32x4 m = (f32x4){-1e30f, -1e30f, -1e30f, -1e30f};
    f32x4 l = (f32x4){0.f, 0.f, 0.f, 0.f};

    const int krow = t >> 2, kseg = t & 3;
    const int vrow = t >> 1, vseg = t & 1;

    for (int k0 = ks; k0 < ke; k0 += 64) {
        __syncthreads();
        {
            const u32x4* src = reinterpret_cast<const u32x4*>(
                &Kf[(size_t)(k0 + krow) * DIM + h * HD + kseg * 32]);
            u32x4 v0 = src[0], v1 = src[1], v2 = src[2], v3 = src[3];
            u32x4* dst = reinterpret_cast<u32x4*>(&Ks[krow][kseg * 32]);
            dst[0] = v0; dst[1] = v1; dst[2] = v2; dst[3] = v3;
        }
        {
            const u32x4* src = reinterpret_cast<const u32x4*>(
                &VTg[(size_t)(h * HD + vrow) * STOT + k0 + vseg * 32]);
            u32x4 v0 = src[0], v1 = src[1], v2 = src[2], v3 = src[3];
            u32x4* dst = reinterpret_cast<u32x4*>(&VTs[vrow][vseg * 32]);
            dst[0] = v0; dst[1] = v1; dst[2] = v2; dst[3] = v3;
        }
        __syncthreads();

        f32x4 s[4];
        #pragma unroll
        for (int kt = 0; kt < 4; kt++) {
            f32x4 a = (f32x4){0.f, 0.f, 0.f, 0.f};
            #pragma unroll
            for (int c = 0; c < 4; c++) {
                bf16x8 kf = *reinterpret_cast<const bf16x8*>(
                    &Ks[kt * 16 + col][c * 32 + quad * 8]);
                a = __builtin_amdgcn_mfma_f32_16x16x32_bf16(Qfrag[c], kf, a, 0, 0, 0);
            }
            s[kt] = a * SOFTMAX_SCALE;
        }

        f32x4 tmax = max4(max4(s[0], s[1]), max4(s[2], s[3]));
        tmax = max4(tmax, shfl_xor4(tmax, 1));
        tmax = max4(tmax, shfl_xor4(tmax, 2));
        tmax = max4(tmax, shfl_xor4(tmax, 4));
        tmax = max4(tmax, shfl_xor4(tmax, 8));
        f32x4 mnew = max4(m, tmax);
        f32x4 alpha, rowsum = (f32x4){0.f, 0.f, 0.f, 0.f};
        #pragma unroll
        for (int r = 0; r < 4; r++) alpha[r] = __expf(m[r] - mnew[r]);
        f32x4 p[4];
        #pragma unroll
        for (int kt = 0; kt < 4; kt++)
            #pragma unroll
            for (int r = 0; r < 4; r++) {
                p[kt][r] = __expf(s[kt][r] - mnew[r]);
                rowsum[r] += p[kt][r];
            }
        rowsum += shfl_xor4(rowsum, 1);
        rowsum += shfl_xor4(rowsum, 2);
        rowsum += shfl_xor4(rowsum, 4);
        rowsum += shfl_xor4(rowsum, 8);
        #pragma unroll
        for (int r = 0; r < 4; r++) l[r] = l[r] * alpha[r] + rowsum[r];
        m = mnew;
        #pragma unroll
        for (int dt = 0; dt < 8; dt++)
            #pragma unroll
            for (int r = 0; r < 4; r++) O[dt][r] *= alpha[r];

        #pragma unroll
        for (int kt = 0; kt < 4; kt++)
            #pragma unroll
            for (int r = 0; r < 4; r++)
                Ps[w][quad * 4 + r][kt * 16 + col] = f2b(p[kt][r]);

        #pragma unroll
        for (int c = 0; c < 2; c++) {
            bf16x8 pf = *reinterpret_cast<const bf16x8*>(
                &Ps[w][col][c * 32 + quad * 8]);
            #pragma unroll
            for (int dt = 0; dt < 8; dt++) {
                bf16x8 vf = *reinterpret_cast<const bf16x8*>(
                    &VTs[dt * 16 + col][c * 32 + quad * 8]);
                O[dt] = __builtin_amdgcn_mfma_f32_16x16x32_bf16(pf, vf, O[dt], 0, 0, 0);
            }
        }
    }

    f32x4 inv;
    #pragma unroll
    for (int r = 0; r < 4; r++) inv[r] = 1.0f / l[r];
    #pragma unroll
    for (int dt = 0; dt < 8; dt++)
        #pragma unroll
        for (int r = 0; r < 4; r++)
            AO[(size_t)(q0 + w * 16 + quad * 4 + r) * DIM + h * HD + dt * 16 + col] =
                f2b(O[dt][r] * inv[r]);
}

// ---------------------------------------------------------------------------
// Buffer plan:
//   Qf/AO = d_ws            [STOT*DIM bf16] 15.7 MB
//   WT    = d_ws + 15.7 MB  [up to DIM*DIM bf16] (tiered on ws_size)
//   Kf    = d_out lower     [STOT*DIM bf16]
//   VTg   = d_out upper     [DIM][STOT] bf16
// ---------------------------------------------------------------------------
extern "C" void kernel_launch(void* const* d_in, const int* in_sizes, int n_in,
                              void* d_out, int out_size, void* d_ws, size_t ws_size,
                              hipStream_t stream)
{
    const void*  hs  = d_in[0];
    const void*  enc = d_in[1];
    const float* rc  = (const float*)d_in[2];
    const float* rs  = (const float*)d_in[3];
    const float* wq  = (const float*)d_in[4];  const float* bq  = (const float*)d_in[5];
    const float* wk  = (const float*)d_in[6];  const float* bk  = (const float*)d_in[7];
    const float* wv  = (const float*)d_in[8];  const float* bv  = (const float*)d_in[9];
    const float* waq = (const float*)d_in[10]; const float* baq = (const float*)d_in[11];
    const float* wak = (const float*)d_in[12]; const float* bak = (const float*)d_in[13];
    const float* wav = (const float*)d_in[14]; const float* bav = (const float*)d_in[15];
    const float* nq  = (const float*)d_in[16]; const float* nk  = (const float*)d_in[17];
    const float* naq = (const float*)d_in[18]; const float* nak = (const float*)d_in[19];
    const float* wo  = (const float*)d_in[20]; const float* bo  = (const float*)d_in[21];
    const float* wao = (const float*)d_in[22]; const float* bao = (const float*)d_in[23];

    const size_t QFB = (size_t)STOT * DIM * sizeof(u16);      // 15,728,640
    const size_t WTF = (size_t)DIM * DIM * sizeof(u16);       // 18,874,368
    u16* Qf  = (u16*)d_ws;
    u16* WT  = (u16*)((char*)d_ws + QFB);
    u16* Kf  = (u16*)d_out;
    u16* VTg = (u16*)d_out + (size_t)STOT * DIM;
    u16* AO  = Qf;

    dim3 blk(256);

    int nchunk;
    if      (ws_size >= QFB + WTF)     nchunk = DIM;
    else if (ws_size >= QFB + WTF / 2) nchunk = DIM / 2;
    else                               nchunk = 0;

    if (nchunk > 0) {
        dim3 tgrid(DIM / 64, nchunk / 64);
        #define RUN_GEMM(AF32_, MODE_, MT_, Aptr, Wptr, Bias, Cptr, Coff, M_)     \
            for (int nb = 0; nb < DIM; nb += nchunk) {                            \
                transpose_w_kernel<<<tgrid, blk, 0, stream>>>(Wptr, WT, DIM, DIM, nb); \
                gemm_bt_kernel<AF32_, MODE_, MT_><<<dim3((M_) / MT_, nchunk / 128), blk, 0, stream>>>( \
                    Aptr, WT, Bias, Cptr, Coff, M_, DIM, DIM, nb);                \
            }
        RUN_GEMM(1, 0, 128, hs,  wq,  bq,  Qf,  (size_t)TXT * DIM, SEQ)
        RUN_GEMM(1, 0, 128, hs,  wk,  bk,  Kf,  (size_t)TXT * DIM, SEQ)
        RUN_GEMM(1, 2, 128, hs,  wv,  bv,  VTg, (size_t)TXT,       SEQ)
        RUN_GEMM(1, 0, 64,  enc, waq, baq, Qf,  0,                 TXT)
        RUN_GEMM(1, 0, 64,  enc, wak, bak, Kf,  0,                 TXT)
        RUN_GEMM(1, 2, 64,  enc, wav, bav, VTg, 0,                 TXT)
        rmsrope_kernel<<<dim3(NH, STOT / 4, 2), blk, 0, stream>>>(Qf, Kf, nq, nk, naq, nak, rc, rs);
        attn_kernel<<<dim3(STOT / 64, NH), blk, 0, stream>>>(Qf, Kf, VTg, AO);
        RUN_GEMM(0, 1, 128, AO + (size_t)TXT * DIM, wo,  bo,  d_out, 0,                 SEQ)
        RUN_GEMM(0, 1, 64,  AO,                     wao, bao, d_out, (size_t)SEQ * DIM, TXT)
        #undef RUN_GEMM
    } else {
        gemm_bias_kernel<1,0><<<dim3(SEQ / 128, DIM / 128), blk, 0, stream>>>(hs, wq, bq, Qf, (size_t)TXT * DIM, SEQ, DIM, DIM);
        gemm_bias_kernel<1,0><<<dim3(SEQ / 128, DIM / 128), blk, 0, stream>>>(hs, wk, bk, Kf, (size_t)TXT * DIM, SEQ, DIM, DIM);
        gemm_bias_kernel<1,2><<<dim3(SEQ / 128, DIM / 128), blk, 0, stream>>>(hs, wv, bv, VTg, (size_t)TXT, SEQ, DIM, DIM);
        gemm_bias_kernel<1,0><<<dim3(TXT / 128, DIM / 128), blk, 0, stream>>>(enc, waq, baq, Qf, 0, TXT, DIM, DIM);
        gemm_bias_kernel<1,0><<<dim3(TXT / 128, DIM / 128), blk, 0, stream>>>(enc, wak, bak, Kf, 0, TXT, DIM, DIM);
        gemm_bias_kernel<1,2><<<dim3(TXT / 128, DIM / 128), blk, 0, stream>>>(enc, wav, bav, VTg, 0, TXT, DIM, DIM);
        rmsrope_kernel<<<dim3(NH, STOT / 4, 2), blk, 0, stream>>>(Qf, Kf, nq, nk, naq, nak, rc, rs);
        attn_kernel<<<dim3(STOT / 64, NH), blk, 0, stream>>>(Qf, Kf, VTg, AO);
        gemm_bias_kernel<0,1><<<dim3(SEQ / 128, DIM / 128), blk, 0, stream>>>(AO + (size_t)TXT * DIM, wo, bo, d_out, 0, SEQ, DIM, DIM);
        gemm_bias_kernel<0,1><<<dim3(TXT / 128, DIM / 128), blk, 0, stream>>>(AO, wao, bao, d_out, (size_t)SEQ * DIM, TXT, DIM, DIM);
    }
}